// Round 7
// baseline (263.135 us; speedup 1.0000x reference)
//
#include <hip/hip_runtime.h>
#include <hip/hip_bf16.h>
#include <stdint.h>

#define BROWS 16384
#define DIM   256
#define BM    128
#define BN    128
#define NBM   (BROWS / BM)      // 128 row blocks
#define NCHUNK 256              // 64-wide column chunks per row

#define LOG2E 1.44269504088896340736f

typedef __attribute__((ext_vector_type(8))) int  i32x8;
typedef __attribute__((ext_vector_type(4))) float f32x4;
typedef unsigned char uchar;

// ---------------- Kernel A: normalize BOTH matrices + exact diag ------------
// One wave per row-pair: o8 = fp8(o * rsqrt(oo) * log2e), t8 = fp8(t * rsqrt(tt)),
// dlog[row] = <o,t>/(|o||t|) (exact f32, so only logZ carries fp8 noise).
__global__ void normalize_both(const float* __restrict__ o,
                               const float* __restrict__ t,
                               uchar* __restrict__ o8,
                               uchar* __restrict__ t8,
                               float* __restrict__ dlog) {
  int row  = blockIdx.x * 4 + (threadIdx.x >> 6);
  int lane = threadIdx.x & 63;
  float4 a = *(reinterpret_cast<const float4*>(o + (size_t)row * DIM) + lane);
  float4 b = *(reinterpret_cast<const float4*>(t + (size_t)row * DIM) + lane);
  float sso = a.x * a.x + a.y * a.y + a.z * a.z + a.w * a.w;
  float sst = b.x * b.x + b.y * b.y + b.z * b.z + b.w * b.w;
  float d   = a.x * b.x + a.y * b.y + a.z * b.z + a.w * b.w;
#pragma unroll
  for (int m = 1; m < 64; m <<= 1) {
    sso += __shfl_xor(sso, m);
    sst += __shfl_xor(sst, m);
    d   += __shfl_xor(d, m);
  }
  float ro = rsqrtf(sso);
  float rt = rsqrtf(sst);
  if (lane == 0) dlog[row] = d * ro * rt;
  float qo = ro * LOG2E;
  int wo = 0, wt = 0;
  wo = __builtin_amdgcn_cvt_pk_fp8_f32(a.x * qo, a.y * qo, wo, false);
  wo = __builtin_amdgcn_cvt_pk_fp8_f32(a.z * qo, a.w * qo, wo, true);
  wt = __builtin_amdgcn_cvt_pk_fp8_f32(b.x * rt, b.y * rt, wt, false);
  wt = __builtin_amdgcn_cvt_pk_fp8_f32(b.z * rt, b.w * rt, wt, true);
  reinterpret_cast<int*>(o8 + (size_t)row * DIM)[lane] = wo;
  reinterpret_cast<int*>(t8 + (size_t)row * DIM)[lane] = wt;
}

// ---------------- Kernel B: fp8 GEMM (MX scale=1) + exp2 + partial sums -----
// 128x128 C-tile, 4 waves 2x2 (wave tile 64x64), mfma_scale 16x16x128 fp8,
// identity E8M0 scales. NO LDS, NO barriers: per-lane MFMA fragments are 32
// contiguous bytes of one row -> loaded straight from global (L2/L3-resident;
// A+B = 8 MB total, 64 KB/block) as one i32x8 each (2x global_load_dwordx4).
// Frag (HW-verified rounds 5/6): lane l holds row (l&15), K-bytes
// [(l>>4)*32, +32). C/D: col = lane&15, row = (lane>>4)*4 + reg.
__global__ __launch_bounds__(256, 3) void gemm_expsum(
    const uchar* __restrict__ A8,   // ohat fp8, pre-scaled by log2e
    const uchar* __restrict__ B8,   // that fp8 (rows = logits cols)
    float* __restrict__ partial) {
  int tid  = threadIdx.x;
  int lane = tid & 63;
  int wid  = tid >> 6;
  int wr   = wid >> 1;      // wave row 0..1
  int wc   = wid & 1;       // wave col 0..1
  int bm   = blockIdx.x & (NBM - 1);
  int bn   = blockIdx.x >> 7;

  const int fr = lane & 15;
  const int kc = lane >> 4;    // 0..3: which 32-byte K-chunk this lane owns

  // per-lane fragment base pointers (row fr of the wave's first frag)
  const uchar* pa = A8 + (size_t)(bm * BM + wr * 64 + fr) * DIM + kc * 32;
  const uchar* pb = B8 + (size_t)(bn * BN + wc * 64 + fr) * DIM + kc * 32;

  f32x4 acc[4][4];
#pragma unroll
  for (int m = 0; m < 4; ++m)
#pragma unroll
    for (int n = 0; n < 4; ++n) acc[m][n] = (f32x4){0.f, 0.f, 0.f, 0.f};

#pragma unroll
  for (int kt = 0; kt < 2; ++kt) {   // K = 256 fp8 = 2 x 128
    i32x8 af[4], bf[4];
#pragma unroll
    for (int m = 0; m < 4; ++m)
      af[m] = *reinterpret_cast<const i32x8*>(pa + m * 16 * DIM + kt * 128);
#pragma unroll
    for (int n = 0; n < 4; ++n)
      bf[n] = *reinterpret_cast<const i32x8*>(pb + n * 16 * DIM + kt * 128);
#pragma unroll
    for (int m = 0; m < 4; ++m)
#pragma unroll
      for (int n = 0; n < 4; ++n)
        acc[m][n] = __builtin_amdgcn_mfma_scale_f32_16x16x128_f8f6f4(
            af[m], bf[n], acc[m][n], 0, 0,            // cbsz=fp8, blgp=fp8
            0, 0x7F7F7F7F, 0, 0x7F7F7F7F);            // identity E8M0 scales
  }

  // ---- epilogue: S = log2e * logit (bounded) -> v[j] = sum_n 2^S ----
  float v[16];
#pragma unroll
  for (int j = 0; j < 16; ++j) {
    int m = j >> 2, r = j & 3;
    v[j] = exp2f(acc[m][0][r]) + exp2f(acc[m][1][r]) +
           exp2f(acc[m][2][r]) + exp2f(acc[m][3][r]);
  }
  // butterfly-bisect over the 16 fragment columns: 15 shfl; lane ends with the
  // full column-sum for output row-index j = lane&15. (HW-verified r5/r6.)
#pragma unroll
  for (int s = 0; s < 4; ++s) {
    const int len = 16 >> s;
    const int bit = (lane >> s) & 1;
#pragma unroll
    for (int t = 0; t < 8; ++t) {
      if (t < (len >> 1)) {
        float a = v[2 * t], b = v[2 * t + 1];
        float recv = __shfl_xor(bit ? a : b, 1 << s);
        v[t] = (bit ? b : a) + recv;
      }
    }
  }
  {
    int j     = lane & 15;
    int sub   = lane >> 4;
    int row   = bm * BM + wr * 64 + (j >> 2) * 16 + sub * 4 + (j & 3);
    int chunk = (bn << 1) | wc;
    partial[(size_t)row * NCHUNK + chunk] = v[0];
  }
}

// ---------------- Kernel C: per-row finish: log(sum) - exact diag ----------
__global__ void row_finish(const float* __restrict__ partial,
                           const float* __restrict__ dlog,
                           float* __restrict__ rowloss) {
  int row  = blockIdx.x * 4 + (threadIdx.x >> 6);
  int lane = threadIdx.x & 63;
  float4 p = *(reinterpret_cast<const float4*>(partial + (size_t)row * NCHUNK) + lane);
  float s  = p.x + p.y + p.z + p.w;
#pragma unroll
  for (int m = 1; m < 64; m <<= 1) s += __shfl_xor(s, m);
  if (lane == 0) rowloss[row] = logf(s) - dlog[row];
}

// ---------------- Kernel D: mean over rows -> d_out[0] ----------------
__global__ void final_reduce(const float* __restrict__ rl, float* __restrict__ out) {
  __shared__ float sm[16];
  float s = 0.f;
  for (int i = threadIdx.x; i < BROWS; i += 1024) s += rl[i];
#pragma unroll
  for (int m = 1; m < 64; m <<= 1) s += __shfl_xor(s, m);
  int wid = threadIdx.x >> 6, lane = threadIdx.x & 63;
  if (lane == 0) sm[wid] = s;
  __syncthreads();
  if (wid == 0) {
    float v = (lane < 16) ? sm[lane] : 0.f;
#pragma unroll
    for (int m = 1; m < 16; m <<= 1) v += __shfl_xor(v, m);
    if (lane == 0) out[0] = v / (float)BROWS;
  }
}

extern "C" void kernel_launch(void* const* d_in, const int* in_sizes, int n_in,
                              void* d_out, int out_size, void* d_ws, size_t ws_size,
                              hipStream_t stream) {
  const float* outputs = (const float*)d_in[0];
  const float* targets = (const float*)d_in[1];
  float* out = (float*)d_out;
  char* ws = (char*)d_ws;

  uchar* o8      = (uchar*)ws;                                      // 4 MB
  uchar* t8      = (uchar*)(ws + (size_t)4 * 1024 * 1024);          // 4 MB
  float* partial = (float*)(ws + (size_t)8 * 1024 * 1024);          // 16 MB
  float* dlog    = (float*)(ws + (size_t)24 * 1024 * 1024);         // 64 KB
  float* rowloss = (float*)(ws + (size_t)24 * 1024 * 1024 + 65536); // 64 KB

  normalize_both<<<BROWS / 4, 256, 0, stream>>>(outputs, targets, o8, t8, dlog);
  gemm_expsum<<<NBM * (BROWS / BN), 256, 0, stream>>>(o8, t8, partial);
  row_finish<<<BROWS / 4, 256, 0, stream>>>(partial, dlog, rowloss);
  final_reduce<<<1, 1024, 0, stream>>>(rowloss, out);
}